// Round 1
// baseline (36.347 us; speedup 1.0000x reference)
//
#include <hip/hip_runtime.h>
#include <stdint.h>

// Radius-graph edge list, B=4, N=2048, cutoff 5.0.
// Output [2, B*P] int32: compacted valid edges (ascending flat index), -1 pad.
//
// Round-7 restructure: move the 67 MB "-1 fill" OUT of pass1 and INTO the
// scatter pass, clamped to positions >= total_edge_count.
//   - Positions [0, total) of each row are exactly the valid edges (dense
//     compaction); [total, kTotal) are exactly the -1 pad. The scatter pass
//     already reads all counts for its self-service prefix, so it gets
//     `total` for one extra reduce. Fill targets (>= total) and edge targets
//     (< total) are disjoint -> no inter-block race, no ordering assumption.
//   - pass1 becomes pure compute (counts + stash only, ~0.2 MB writes): the
//     8.4M pair tests are ~1-2 us of VALU against L2-resident x.
//   - fill_scatter is HBM-write-bound (67 MB); the 16 KB-per-block counts
//     read (L2-hot) and the prefix reduction hide under the store stream.
// Pipeline stays 2 kernels, NO inter-block spin (round-6's lookback
// cross-XCD polling was a 2.3x disaster).

namespace {
constexpr int kB = 4;
constexpr int kN = 2048;
constexpr int kP = kN * (kN - 1) / 2;              // 2096128
constexpr long long kTotal = (long long)kB * kP;   // 8384512
constexpr int kBlock = 256;
constexpr int kItems = 8;
constexpr int kChunk = kBlock * kItems;            // 2048
constexpr int kNBlk = (int)(kTotal / kChunk);      // 4094 (exact, no tail)
constexpr float kCut2 = 25.0f;                     // 5.0^2
constexpr int kCap = 128;                          // stash slots per block
}  // namespace

// p in [0,P) -> (i,j), i<j, triu row-major. Closed-form sqrt guess + exact
// integer fixup. C(i) = i*(4095-i)/2. disc < 2^24 so float sqrt is tight.
__device__ __forceinline__ void decode_pair(int p, int& i, int& j) {
  float t = sqrtf((float)(16769025 - 8 * p));
  int ii = (int)((4095.0f - t) * 0.5f);
  ii = ii < 0 ? 0 : (ii > kN - 2 ? kN - 2 : ii);
  while (ii > 0 && (ii * (4095 - ii)) / 2 > p) --ii;
  while (ii < kN - 2 && ((ii + 1) * (4094 - ii)) / 2 <= p) ++ii;
  i = ii;
  j = ii + 1 + (p - (ii * (4095 - ii)) / 2);
}

__device__ __forceinline__ bool pair_test(const float* __restrict__ x, int b, int p,
                                          int& gi, int& gj) {
  int i, j;
  decode_pair(p, i, j);
  const float* xb = x + (size_t)b * kN * 3;
  float dx = xb[3 * i + 0] - xb[3 * j + 0];
  float dy = xb[3 * i + 1] - xb[3 * j + 1];
  float dz = xb[3 * i + 2] - xb[3 * j + 2];
  gi = b * kN + i;
  gj = b * kN + j;
  return dx * dx + dy * dy + dz * dz <= kCut2;
}

__global__ __launch_bounds__(kBlock) void pass1_kernel(const float* __restrict__ x,
                                                       uint32_t* __restrict__ counts,
                                                       int2* __restrict__ stash) {
  const int t = threadIdx.x;
  const int wave = t >> 6, lane = t & 63;
  const int bid = blockIdx.x;
  const int base = bid * kChunk;

  if (bid == 0 && t < 2) counts[kNBlk + t] = 0;  // pad so pass2 can uint4-load

  // One sqrt-decode per thread per block, then incremental row-walk (+256/item).
  int b = base / kP;
  int p = base - b * kP + t;
  if (p >= kP) { p -= kP; ++b; }
  int i, j;
  decode_pair(p, i, j);
  int ib = b * kN;  // point-index base of batch b

  const float3* __restrict__ x3 = (const float3*)x;
  float3 pi = x3[ib + i];

  uint32_t hits = 0;  // bit k = item k is an edge
#pragma unroll
  for (int k = 0; k < kItems; ++k) {
    float3 pj = x3[ib + j];
    float dx = pi.x - pj.x, dy = pi.y - pj.y, dz = pi.z - pj.z;
    if (dx * dx + dy * dy + dz * dz <= kCut2) hits |= (1u << k);
    if (k < kItems - 1) {
      j += kBlock;
      if (j >= kN) {  // ~20% of items, mostly wave-coherent
        do {
          int ex = j - kN;
          ++i;
          if (i >= kN - 1) { i = 0; ib += kN; }
          j = i + 1 + ex;
        } while (j >= kN);
        pi = x3[ib + i];
      }
    }
  }

  __shared__ uint32_t slot[32];
  if (t < 32) slot[t] = 0;
  __syncthreads();

  const bool waveany = (__ballot(hits != 0) != 0ULL);  // wave-uniform
  if (waveany) {
#pragma unroll
    for (int k = 0; k < kItems; ++k) {
      unsigned long long m = __ballot((hits >> k) & 1u);
      if (m != 0ULL && lane == 0) slot[k * 4 + wave] = (uint32_t)__popcll(m);
    }
  }
  __syncthreads();
  if (t < 32) {  // exclusive scan of 32 (item,wave) counts; write block total
    uint32_t v = slot[t];
    uint32_t run = v;
    for (int off = 1; off < 32; off <<= 1) {
      uint32_t u = __shfl_up(run, off, 64);
      if (t >= off) run += u;
    }
    slot[t] = run - v;
    if (t == 31) counts[bid] = run;
  }
  __syncthreads();
  if (waveany) {
#pragma unroll
    for (int k = 0; k < kItems; ++k) {
      bool f = (hits >> k) & 1u;
      unsigned long long m = __ballot(f);
      if (m != 0ULL && f) {  // rare: ~3 hits per block total
        int pf = base + k * kBlock + t;
        int hb = pf / kP;
        int hp = pf - hb * kP;
        int hi, hj;
        decode_pair(hp, hi, hj);
        uint32_t pos = slot[k * 4 + wave] +
                       (uint32_t)__popcll(m & ((1ULL << lane) - 1ULL));
        if (pos < (uint32_t)kCap)
          stash[(size_t)bid * kCap + pos] = make_int2(hb * kN + hi, hb * kN + hj);
      }
    }
  }
}

__global__ __launch_bounds__(kBlock) void fill_scatter_kernel(
    const float* __restrict__ x, const uint32_t* __restrict__ counts,
    const int2* __restrict__ stash, int* __restrict__ out) {
  const int bid = blockIdx.x;
  const int t = threadIdx.x;
  const int wave = t >> 6, lane = t & 63;

  // Self-service prefix from 16 KB L2-hot counts: below = sum(counts[idx<bid])
  // and tot = sum(all counts) in one pass.
  const uint4* c4 = (const uint4*)counts;  // [4096] incl. zero pad
  uint32_t below = 0, tot = 0;
#pragma unroll
  for (int q = 0; q < 4; ++q) {
    uint4 v = c4[t * 4 + q];
    int i0 = t * 16 + q * 4;
    below += (i0 + 0 < bid) ? v.x : 0u;
    below += (i0 + 1 < bid) ? v.y : 0u;
    below += (i0 + 2 < bid) ? v.z : 0u;
    below += (i0 + 3 < bid) ? v.w : 0u;
    tot += v.x + v.y + v.z + v.w;
  }
  for (int o = 32; o > 0; o >>= 1) {
    below += __shfl_down(below, o, 64);
    tot += __shfl_down(tot, o, 64);
  }
  __shared__ uint32_t wb[4], wt[4];
  if (lane == 0) { wb[wave] = below; wt[wave] = tot; }
  __syncthreads();
  if (t == 0) {
    wb[0] = wb[0] + wb[1] + wb[2] + wb[3];
    wt[0] = wt[0] + wt[1] + wt[2] + wt[3];
  }
  __syncthreads();
  const uint32_t off = wb[0];
  const uint32_t total = wt[0];

  // -1 fill of this block's slice, clamped to positions >= total. Positions
  // < total are exactly the valid edges, written below by their source
  // blocks -> disjoint targets, no race.
  const int base = bid * kChunk;
  {
    const int4 m1 = make_int4(-1, -1, -1, -1);
#pragma unroll
    for (int r = 0; r < 2; ++r) {
      int* __restrict__ row = out + (size_t)r * kTotal;
#pragma unroll
      for (int s = 0; s < 2; ++s) {
        const int f = base + ((s * kBlock + t) << 2);
        if ((uint32_t)f >= total) {
          *(int4*)(row + f) = m1;
        } else if ((uint32_t)f + 4u > total) {  // straddles the boundary
          for (int e = 0; e < 4; ++e)
            if ((uint32_t)(f + e) >= total) row[f + e] = -1;
        }
      }
    }
  }

  const uint32_t cnt = counts[bid];
  if (cnt == 0) return;  // wave-uniform (cnt is block-uniform)

  if (cnt <= (uint32_t)kCap) {
    for (uint32_t e = t; e < cnt; e += kBlock) {
      int2 v = stash[(size_t)bid * kCap + e];
      out[off + e] = v.x;
      out[(size_t)kTotal + off + e] = v.y;
    }
    return;
  }
  // Overflow fallback (count > kCap): recompute this block's edges with
  // ballot ranks and write directly. Deterministic + exact.
  const int bb0 = base / kP;
  const int p0 = base - bb0 * kP;
  __shared__ uint32_t slot[kItems * 4];
  unsigned long long masks[kItems];
  int gi[kItems], gj[kItems];
  bool fl[kItems];
  for (int k = 0; k < kItems; ++k) {
    int o = k * kBlock + t;
    int b = bb0, p = p0 + o;
    if (p >= kP) { p -= kP; ++b; }
    fl[k] = pair_test(x, b, p, gi[k], gj[k]);
    masks[k] = __ballot(fl[k]);
    if (lane == 0) slot[k * 4 + wave] = (uint32_t)__popcll(masks[k]);
  }
  __syncthreads();
  if (t == 0) {
    uint32_t run = 0;
    for (int s = 0; s < kItems * 4; ++s) {
      uint32_t c = slot[s];
      slot[s] = run;
      run += c;
    }
  }
  __syncthreads();
  for (int k = 0; k < kItems; ++k) {
    if (fl[k]) {
      uint32_t pos = off + slot[k * 4 + wave] +
                     (uint32_t)__popcll(masks[k] & ((1ULL << lane) - 1ULL));
      out[pos] = gi[k];
      out[(size_t)kTotal + pos] = gj[k];
    }
  }
}

extern "C" void kernel_launch(void* const* d_in, const int* in_sizes, int n_in,
                              void* d_out, int out_size, void* d_ws, size_t ws_size,
                              hipStream_t stream) {
  const float* x = (const float*)d_in[0];
  int* out = (int*)d_out;
  uint32_t* counts = (uint32_t*)d_ws;                 // [4096] (2 pad)
  int2* stash = (int2*)(counts + 4096);               // [4094 * kCap] ~4.2 MB

  hipLaunchKernelGGL(pass1_kernel, dim3(kNBlk), dim3(kBlock), 0, stream, x, counts,
                     stash);
  hipLaunchKernelGGL(fill_scatter_kernel, dim3(kNBlk), dim3(kBlock), 0, stream, x,
                     counts, stash, out);
}

// Round 2
// 35.272 us; speedup vs baseline: 1.0305x; 1.0305x over previous
//
#include <hip/hip_runtime.h>
#include <stdint.h>

// Radius-graph edge list, B=4, N=2048, cutoff 5.0.
// Output [2, B*P] int32: compacted valid edges (ascending flat index), -1 pad.
//
// Round-8: round-0 structure restored (the -1 fill lives in pass1 where it
// issues with zero dependencies and overlaps the pair-test compute; round-7
// proved moving it behind the scatter prefix costs ~4 us). Scatter shrunk
// 16x: 256 blocks x 16 pass1-blocks each, instead of 4094 blocks each
// redundantly reading all 16 KB of counts (64 MB L2 -> 4 MB L2, and a
// 4094-block dispatch ramp eliminated for ~12K edges of real work).
//   pass1  : fill own out-slice with -1; incremental (b,i,j) row-walk with
//            cached pi; hot loop accumulates an 8-bit hit mask/thread;
//            epilogue: ballots + 32-slot scan + count + stash (kCap=128).
//   scatter: 256 blocks; each loads ALL 4096 counts (16 KB, L2-hot),
//            block-reduces counts[idx < rangeStart] for its global offset,
//            scans its 16 in-range counts in LDS, then copies those stashes
//            to final positions (recompute fallback if count > kCap).
// NO inter-block spin (round-6's lookback cross-XCD polling was a 2.3x
// disaster, VALUBusy 6.7%).

namespace {
constexpr int kB = 4;
constexpr int kN = 2048;
constexpr int kP = kN * (kN - 1) / 2;              // 2096128
constexpr long long kTotal = (long long)kB * kP;   // 8384512
constexpr int kBlock = 256;
constexpr int kItems = 8;
constexpr int kChunk = kBlock * kItems;            // 2048
constexpr int kNBlk = (int)(kTotal / kChunk);      // 4094 (exact, no tail)
constexpr float kCut2 = 25.0f;                     // 5.0^2
constexpr int kCap = 128;                          // stash slots per block
constexpr int kSB = 16;                            // pass1-blocks per scatter block
constexpr int kScatGrid = (kNBlk + kSB - 1) / kSB; // 256
}  // namespace

// p in [0,P) -> (i,j), i<j, triu row-major. Closed-form sqrt guess + exact
// integer fixup. C(i) = i*(4095-i)/2. disc < 2^24 so float sqrt is tight.
__device__ __forceinline__ void decode_pair(int p, int& i, int& j) {
  float t = sqrtf((float)(16769025 - 8 * p));
  int ii = (int)((4095.0f - t) * 0.5f);
  ii = ii < 0 ? 0 : (ii > kN - 2 ? kN - 2 : ii);
  while (ii > 0 && (ii * (4095 - ii)) / 2 > p) --ii;
  while (ii < kN - 2 && ((ii + 1) * (4094 - ii)) / 2 <= p) ++ii;
  i = ii;
  j = ii + 1 + (p - (ii * (4095 - ii)) / 2);
}

__device__ __forceinline__ bool pair_test(const float* __restrict__ x, int b, int p,
                                          int& gi, int& gj) {
  int i, j;
  decode_pair(p, i, j);
  const float* xb = x + (size_t)b * kN * 3;
  float dx = xb[3 * i + 0] - xb[3 * j + 0];
  float dy = xb[3 * i + 1] - xb[3 * j + 1];
  float dz = xb[3 * i + 2] - xb[3 * j + 2];
  gi = b * kN + i;
  gj = b * kN + j;
  return dx * dx + dy * dy + dz * dz <= kCut2;
}

__global__ __launch_bounds__(kBlock) void pass1_kernel(const float* __restrict__ x,
                                                       uint32_t* __restrict__ counts,
                                                       int2* __restrict__ stash,
                                                       int* __restrict__ out) {
  const int t = threadIdx.x;
  const int wave = t >> 6, lane = t & 63;
  const int bid = blockIdx.x;
  const int base = bid * kChunk;

  // Fill this block's slice of both output rows with -1 (2048 ints each).
  // Zero-dependency stores: issue from cycle 0, overlap the compute below.
  {
    const int4 m1 = make_int4(-1, -1, -1, -1);
    int4* o0 = (int4*)out + (base >> 2);
    int4* o1 = (int4*)(out + kTotal) + (base >> 2);
    o0[t] = m1;
    o0[t + kBlock] = m1;
    o1[t] = m1;
    o1[t + kBlock] = m1;
  }
  if (bid == 0 && t < 2) counts[kNBlk + t] = 0;  // pad so scatter can uint4-load

  // One sqrt-decode per thread per block, then incremental row-walk (+256/item).
  int b = base / kP;
  int p = base - b * kP + t;
  if (p >= kP) { p -= kP; ++b; }
  int i, j;
  decode_pair(p, i, j);
  int ib = b * kN;  // point-index base of batch b

  const float3* __restrict__ x3 = (const float3*)x;
  float3 pi = x3[ib + i];

  uint32_t hits = 0;  // bit k = item k is an edge
#pragma unroll
  for (int k = 0; k < kItems; ++k) {
    float3 pj = x3[ib + j];
    float dx = pi.x - pj.x, dy = pi.y - pj.y, dz = pi.z - pj.z;
    if (dx * dx + dy * dy + dz * dz <= kCut2) hits |= (1u << k);
    if (k < kItems - 1) {
      j += kBlock;
      if (j >= kN) {  // ~20% of items, mostly wave-coherent
        do {
          int ex = j - kN;
          ++i;
          if (i >= kN - 1) { i = 0; ib += kN; }
          j = i + 1 + ex;
        } while (j >= kN);
        pi = x3[ib + i];
      }
    }
  }

  __shared__ uint32_t slot[32];
  if (t < 32) slot[t] = 0;
  __syncthreads();

  const bool waveany = (__ballot(hits != 0) != 0ULL);  // wave-uniform
  if (waveany) {
#pragma unroll
    for (int k = 0; k < kItems; ++k) {
      unsigned long long m = __ballot((hits >> k) & 1u);
      if (m != 0ULL && lane == 0) slot[k * 4 + wave] = (uint32_t)__popcll(m);
    }
  }
  __syncthreads();
  if (t < 32) {  // exclusive scan of 32 (item,wave) counts; write block total
    uint32_t v = slot[t];
    uint32_t run = v;
    for (int off = 1; off < 32; off <<= 1) {
      uint32_t u = __shfl_up(run, off, 64);
      if (t >= off) run += u;
    }
    slot[t] = run - v;
    if (t == 31) counts[bid] = run;
  }
  __syncthreads();
  if (waveany) {
#pragma unroll
    for (int k = 0; k < kItems; ++k) {
      bool f = (hits >> k) & 1u;
      unsigned long long m = __ballot(f);
      if (m != 0ULL && f) {  // rare: ~3 hits per block total
        int pf = base + k * kBlock + t;
        int hb = pf / kP;
        int hp = pf - hb * kP;
        int hi, hj;
        decode_pair(hp, hi, hj);
        uint32_t pos = slot[k * 4 + wave] +
                       (uint32_t)__popcll(m & ((1ULL << lane) - 1ULL));
        if (pos < (uint32_t)kCap)
          stash[(size_t)bid * kCap + pos] = make_int2(hb * kN + hi, hb * kN + hj);
      }
    }
  }
}

__global__ __launch_bounds__(kBlock) void scatter_kernel(const float* __restrict__ x,
                                                         const uint32_t* __restrict__ counts,
                                                         const int2* __restrict__ stash,
                                                         int* __restrict__ out) {
  const int t = threadIdx.x;
  const int wave = t >> 6, lane = t & 63;
  const int pbBase = blockIdx.x * kSB;  // first pass1-block in this range

  // Global offset of this range: sum(counts[idx < pbBase]) from 16 KB L2-hot.
  // pbBase % 4 == 0, so each uint4 is entirely in or out of the prefix.
  const uint4* c4 = (const uint4*)counts;  // [4096] incl. zero pad
  uint32_t below = 0;
#pragma unroll
  for (int q = 0; q < 4; ++q) {
    uint4 v = c4[t * 4 + q];
    int i0 = t * 16 + q * 4;
    if (i0 + 4 <= pbBase) below += v.x + v.y + v.z + v.w;
  }
  for (int o = 32; o > 0; o >>= 1) below += __shfl_down(below, o, 64);
  __shared__ uint32_t wred[4];
  __shared__ uint32_t scnt[kSB];   // in-range counts
  __shared__ uint32_t soff[kSB];   // in-range exclusive scan
  if (lane == 0) wred[wave] = below;
  if (t < kSB) {
    int pb = pbBase + t;
    scnt[t] = (pb < kNBlk) ? counts[pb] : 0u;
  }
  __syncthreads();
  if (t == 0) {
    uint32_t base_off = wred[0] + wred[1] + wred[2] + wred[3];
    uint32_t run = base_off;
    for (int r = 0; r < kSB; ++r) {
      soff[r] = run;
      run += scnt[r];
    }
  }
  __syncthreads();

  for (int r = 0; r < kSB; ++r) {  // all branches below are block-uniform
    const int pb = pbBase + r;
    if (pb >= kNBlk) break;
    const uint32_t cnt = scnt[r];
    if (cnt == 0) continue;
    const uint32_t off = soff[r];

    if (cnt <= (uint32_t)kCap) {
      for (uint32_t e = t; e < cnt; e += kBlock) {
        int2 v = stash[(size_t)pb * kCap + e];
        out[off + e] = v.x;
        out[(size_t)kTotal + off + e] = v.y;
      }
      continue;
    }
    // Overflow fallback (count > kCap): recompute this pass1-block's edges
    // with ballot ranks and write directly. Deterministic + exact.
    const int base = pb * kChunk;
    const int bb0 = base / kP;
    const int p0 = base - bb0 * kP;
    __shared__ uint32_t slot[kItems * 4];
    unsigned long long masks[kItems];
    int gi[kItems], gj[kItems];
    bool fl[kItems];
    for (int k = 0; k < kItems; ++k) {
      int o = k * kBlock + t;
      int b = bb0, p = p0 + o;
      if (p >= kP) { p -= kP; ++b; }
      fl[k] = pair_test(x, b, p, gi[k], gj[k]);
      masks[k] = __ballot(fl[k]);
      if (lane == 0) slot[k * 4 + wave] = (uint32_t)__popcll(masks[k]);
    }
    __syncthreads();
    if (t == 0) {
      uint32_t run = 0;
      for (int s = 0; s < kItems * 4; ++s) {
        uint32_t c = slot[s];
        slot[s] = run;
        run += c;
      }
    }
    __syncthreads();
    for (int k = 0; k < kItems; ++k) {
      if (fl[k]) {
        uint32_t pos = off + slot[k * 4 + wave] +
                       (uint32_t)__popcll(masks[k] & ((1ULL << lane) - 1ULL));
        out[pos] = gi[k];
        out[(size_t)kTotal + pos] = gj[k];
      }
    }
    __syncthreads();  // protect slot[] before next overflow pb reuses it
  }
}

extern "C" void kernel_launch(void* const* d_in, const int* in_sizes, int n_in,
                              void* d_out, int out_size, void* d_ws, size_t ws_size,
                              hipStream_t stream) {
  const float* x = (const float*)d_in[0];
  int* out = (int*)d_out;
  uint32_t* counts = (uint32_t*)d_ws;                 // [4096] (2 pad)
  int2* stash = (int2*)(counts + 4096);               // [4094 * kCap] ~4.2 MB

  hipLaunchKernelGGL(pass1_kernel, dim3(kNBlk), dim3(kBlock), 0, stream, x, counts,
                     stash, out);
  hipLaunchKernelGGL(scatter_kernel, dim3(kScatGrid), dim3(kBlock), 0, stream, x,
                     counts, stash, out);
}